// Round 1
// baseline (104.855 us; speedup 1.0000x reference)
//
#include <hip/hip_runtime.h>

// ViewLearner edge-MLP: out[e] = relu(concat(emb[src[e]],emb[dst[e]]) @ W1 + b1) @ W2 + b2
// Strategy: bf16 MFMA (16x16x32). A-fragments gathered directly from a bf16 copy of
// node_emb (built in d_ws by a pre-pass) -- the A layout A[m=lane&15][k=quad*8+j] is
// 8 contiguous bf16 = one dwordx4 per lane per K-chunk. W1^T staged to LDS as bf16 once
// per block; B-fragments pinned in VGPRs across the grid-stride tile loop.

typedef __attribute__((ext_vector_type(8))) short short8;
typedef __attribute__((ext_vector_type(4))) float f32x4;

__device__ __forceinline__ unsigned short f2bf_rne(float f) {
    union { float f; unsigned u; } v;
    v.f = f;
    // round-to-nearest-even truncation to bf16
    return (unsigned short)((v.u + 0x7FFFu + ((v.u >> 16) & 1u)) >> 16);
}

__global__ void cvt_to_bf16(const float* __restrict__ x,
                            unsigned short* __restrict__ y, int n4) {
    int i = blockIdx.x * blockDim.x + threadIdx.x;
    if (i >= n4) return;
    f32x4 v = ((const f32x4*)x)[i];
    ushort4 o;
    o.x = f2bf_rne(v[0]);
    o.y = f2bf_rne(v[1]);
    o.z = f2bf_rne(v[2]);
    o.w = f2bf_rne(v[3]);
    ((ushort4*)y)[i] = o;
}

#define W1T_STRIDE 136  // 128 + 8 shorts pad: frag reads land 2-way max on banks

__global__ void edge_mlp(const int* __restrict__ eidx,
                         const unsigned short* __restrict__ nodebf,
                         const float* __restrict__ W1,
                         const float* __restrict__ b1,
                         const float* __restrict__ W2,
                         const float* __restrict__ b2,
                         float* __restrict__ out,
                         int E, int ntiles) {
    __shared__ __align__(16) unsigned short w1t[64 * W1T_STRIDE];

    const int tid = threadIdx.x;

    // Stage W1^T (bf16) into LDS: w1t[n*W1T_STRIDE + k] = bf16(W1[k*64 + n]).
    // W1 is [128][64] row-major; idx = k*64 + n gives coalesced global reads.
#pragma unroll
    for (int i = 0; i < 32; ++i) {
        int idx = tid + i * 256;
        int k = idx >> 6;
        int n = idx & 63;
        w1t[n * W1T_STRIDE + k] = f2bf_rne(W1[idx]);
    }
    __syncthreads();

    const int lane = tid & 63;
    const int wid = tid >> 6;
    const int c = lane & 15;     // A: edge-in-tile m; B: col n low bits; C: col
    const int quad = lane >> 4;  // 0..3

    // B fragments: bfrag[nt][kc] holds W1[k = kc*32 + quad*8 + j][n = nt*16 + c], j=0..7
    short8 bfrag[4][4];
#pragma unroll
    for (int nt = 0; nt < 4; ++nt)
#pragma unroll
        for (int kc = 0; kc < 4; ++kc) {
            const short8* p =
                (const short8*)&w1t[(nt * 16 + c) * W1T_STRIDE + kc * 32 + quad * 8];
            bfrag[nt][kc] = *p;
        }

    float w2v[4], b1v[4];
#pragma unroll
    for (int nt = 0; nt < 4; ++nt) {
        w2v[nt] = W2[nt * 16 + c];
        b1v[nt] = b1[nt * 16 + c];
    }
    const float b2v = b2[0];

    const int wave_global = blockIdx.x * 4 + wid;
    const int wave_stride = gridDim.x * 4;
    const int ko = quad * 8;  // k offset within a 32-wide chunk

    for (int t = wave_global; t < ntiles; t += wave_stride) {
        int e = t * 16 + c;  // this lane's A-row (edge) within the tile
        int ec = (e < E) ? e : (E - 1);
        int src = eidx[ec];
        int dst = eidx[E + ec];

        const unsigned short* rs = nodebf + (size_t)src * 64;
        const unsigned short* rd = nodebf + (size_t)dst * 64;
        // A row = [emb_src (k 0..63) | emb_dst (k 64..127)]
        short8 a0 = *(const short8*)(rs + ko);       // k  0..31
        short8 a1 = *(const short8*)(rs + 32 + ko);  // k 32..63
        short8 a2 = *(const short8*)(rd + ko);       // k 64..95
        short8 a3 = *(const short8*)(rd + 32 + ko);  // k 96..127

        f32x4 acc[4];
#pragma unroll
        for (int nt = 0; nt < 4; ++nt) acc[nt] = (f32x4){0.f, 0.f, 0.f, 0.f};

#pragma unroll
        for (int nt = 0; nt < 4; ++nt) {
            acc[nt] = __builtin_amdgcn_mfma_f32_16x16x32_bf16(a0, bfrag[nt][0], acc[nt], 0, 0, 0);
            acc[nt] = __builtin_amdgcn_mfma_f32_16x16x32_bf16(a1, bfrag[nt][1], acc[nt], 0, 0, 0);
            acc[nt] = __builtin_amdgcn_mfma_f32_16x16x32_bf16(a2, bfrag[nt][2], acc[nt], 0, 0, 0);
            acc[nt] = __builtin_amdgcn_mfma_f32_16x16x32_bf16(a3, bfrag[nt][3], acc[nt], 0, 0, 0);
        }

        // Epilogue: C layout col=lane&15 (=hid low bits), row=quad*4+reg (=edge).
        // h = relu(C + b1); partial = h * W2[hid]; reduce over the 16 cols.
        float p[4];
#pragma unroll
        for (int r = 0; r < 4; ++r) p[r] = 0.f;
#pragma unroll
        for (int nt = 0; nt < 4; ++nt) {
#pragma unroll
            for (int r = 0; r < 4; ++r) {
                float h = acc[nt][r] + b1v[nt];
                h = fmaxf(h, 0.f);
                p[r] += h * w2v[nt];
            }
        }
#pragma unroll
        for (int m = 1; m < 16; m <<= 1) {
#pragma unroll
            for (int r = 0; r < 4; ++r) p[r] += __shfl_xor(p[r], m, 16);
        }

        if (c == 0) {
            int base = t * 16 + quad * 4;  // 4 consecutive edges for this quad
            if (base + 3 < E) {
                f32x4 o = {p[0] + b2v, p[1] + b2v, p[2] + b2v, p[3] + b2v};
                *(f32x4*)(out + base) = o;
            } else {
#pragma unroll
                for (int r = 0; r < 4; ++r)
                    if (base + r < E) out[base + r] = p[r] + b2v;
            }
        }
    }
}

extern "C" void kernel_launch(void* const* d_in, const int* in_sizes, int n_in,
                              void* d_out, int out_size, void* d_ws, size_t ws_size,
                              hipStream_t stream) {
    const float* node = (const float*)d_in[0];
    const int* eidx = (const int*)d_in[1];
    const float* W1 = (const float*)d_in[2];
    const float* b1 = (const float*)d_in[3];
    const float* W2 = (const float*)d_in[4];
    const float* b2 = (const float*)d_in[5];
    float* out = (float*)d_out;

    const int node_elems = in_sizes[0];  // N_NODES * 64
    const int E = in_sizes[1] / 2;       // edge_index is [2][E]
    const int n4 = node_elems / 4;

    unsigned short* nodebf = (unsigned short*)d_ws;  // bf16 node table, 6.4 MB

    cvt_to_bf16<<<(n4 + 255) / 256, 256, 0, stream>>>(node, nodebf, n4);

    const int ntiles = (E + 15) / 16;
    edge_mlp<<<1024, 256, 0, stream>>>(eidx, nodebf, W1, b1, W2, b2, out, E, ntiles);
}